// Round 14
// baseline (351.417 us; speedup 1.0000x reference)
//
#include <hip/hip_runtime.h>
#include <hip/hip_bf16.h>

typedef __bf16 bf16x8 __attribute__((ext_vector_type(8)));
typedef float f32x4 __attribute__((ext_vector_type(4)));
typedef long i64x2 __attribute__((ext_vector_type(2)));

#define DEVI static __device__ __forceinline__

DEVI void load_lds16(const void* g, void* l) {
  __builtin_amdgcn_global_load_lds(
      (const __attribute__((address_space(1))) void*)g,
      (__attribute__((address_space(3))) void*)l, 16, 0, 0);
}

DEVI unsigned short f2b(float f) { return __bfloat16_as_ushort(__float2bfloat16(f)); }
DEVI float b2f(unsigned short u) {
  union { unsigned int i; float f; } c;
  c.i = ((unsigned int)u) << 16;
  return c.f;
}
DEVI float sigm(float x) { return 1.0f / (1.0f + __expf(-x)); }
DEVI float tanh_fast(float x) { return 2.0f / (1.0f + __expf(-2.0f * x)) - 1.0f; }

// float -> OCP e4m3fn with RNE (hand-rolled; sat to 448, subnormals handled)
DEVI unsigned char f2fp8(float f) {
  const unsigned int u = __float_as_uint(f);
  const unsigned char s = (unsigned char)((u >> 24) & 0x80);
  const float a = fabsf(f);
  if (a >= 448.f) return s | 0x7E;
  if (a < 0.015625f) {  // subnormal range: value = M * 2^-9
    const int M = (int)rintf(a * 512.f);
    if (M > 7) return s | 0x08;
    return s | (unsigned char)M;
  }
  int ex;
  const float m = frexpf(a, &ex);
  int r = (int)rintf(m * 16.f);
  if (r == 16) { r = 8; ex += 1; }
  const int E = ex + 6, M = r - 8;
  if (E > 15 || (E == 15 && M == 7)) return s | 0x7E;
  return s | (unsigned char)((E << 3) | M);
}

// involutive 16B-granule swizzle (64B rows): XOR byte-bits 4-6 with bits 7-9.
// Verified conflict-free for the 16-row fragment/staging patterns (R3-R13).
DEVI int swz(int L) { return L ^ (((L >> 7) & 7) << 4); }

// fp8 image k-index: true col hc -> image byte (pair-tile interleave along K).
DEVI int imgk(int hc) {
  return (hc & ~63) + (((hc >> 3) & 3) << 4) + (((hc >> 5) & 1) << 3) + (hc & 7);
}

// ---------------------------------------------------------------- fused prep (R12-verified)
__global__ __launch_bounds__(256) void prep_kernel(
    const float* __restrict__ x, const float* __restrict__ W,
    const float* __restrict__ U, const float* __restrict__ bW,
    const float* __restrict__ bU, unsigned short* __restrict__ xb,
    unsigned short* __restrict__ Wbp, unsigned char* __restrict__ Up8,
    float* __restrict__ bp) {
  const int bid = blockIdx.x;
  if (bid < 4096) {
    const int i = bid * 256 + threadIdx.x;
    const float4 v = reinterpret_cast<const float4*>(x)[i];
    ushort4 o;
    o.x = f2b(v.x); o.y = f2b(v.y); o.z = f2b(v.z); o.w = f2b(v.w);
    reinterpret_cast<ushort4*>(xb)[i] = o;
  } else if (bid < 8192) {
    const int i = (bid - 4096) * 256 + threadIdx.x;
    const int r = i >> 8;
    const int cw = i & 255;
    const float4 v = reinterpret_cast<const float4*>(W)[i];
    const int rp = ((r & 1023) << 2) + (r >> 10);  // 4h+g
    ushort4 o;
    o.x = f2b(v.x); o.y = f2b(v.y); o.z = f2b(v.z); o.w = f2b(v.w);
    *reinterpret_cast<ushort4*>(&Wbp[(size_t)rp * 1024 + (cw << 2)]) = o;
  } else if (bid < 9216) {
    const int i = (bid - 8192) * 256 + threadIdx.x;
    const int d0 = i << 4;
    const int rp = d0 >> 10;
    const int ik0 = d0 & 1023;
    const int P = ik0 >> 6, q = (ik0 >> 4) & 3;
    const int k0 = P * 64 + q * 8;
    const int srcrow = (rp & 3) * 1024 + (rp >> 2);  // g*1024 + h
    const float* S = U + (size_t)srcrow * 1024;
    const float4 a0 = *reinterpret_cast<const float4*>(S + k0);
    const float4 a1 = *reinterpret_cast<const float4*>(S + k0 + 4);
    const float4 b0 = *reinterpret_cast<const float4*>(S + k0 + 32);
    const float4 b1 = *reinterpret_cast<const float4*>(S + k0 + 36);
    auto pk = [](unsigned char a, unsigned char b, unsigned char c, unsigned char d) {
      return (unsigned)a | ((unsigned)b << 8) | ((unsigned)c << 16) | ((unsigned)d << 24);
    };
    uint4 w;
    w.x = pk(f2fp8(a0.x * 32.f), f2fp8(a0.y * 32.f), f2fp8(a0.z * 32.f), f2fp8(a0.w * 32.f));
    w.y = pk(f2fp8(a1.x * 32.f), f2fp8(a1.y * 32.f), f2fp8(a1.z * 32.f), f2fp8(a1.w * 32.f));
    w.z = pk(f2fp8(b0.x * 32.f), f2fp8(b0.y * 32.f), f2fp8(b0.z * 32.f), f2fp8(b0.w * 32.f));
    w.w = pk(f2fp8(b1.x * 32.f), f2fp8(b1.y * 32.f), f2fp8(b1.z * 32.f), f2fp8(b1.w * 32.f));
    *reinterpret_cast<uint4*>(&Up8[d0]) = w;
  } else {
    const int i = (bid - 9216) * 256 + threadIdx.x;
    const int h = i >> 2, g = i & 3;
    bp[i] = bW[g * 1024 + h] + bU[g * 1024 + h];
  }
}

// ============================ bf16 GEMM (t=0), high-occupancy ================
// 128x128 tile, 4 waves (2x2), per-wave 64x64 -> acc 64 VGPR -> 3 waves/SIMD.
// 3 LDS slots x 16KB (A 8KB | B 8KB, K=32 bf16) = 48KB -> 3 blocks/CU.
// Reg-dbuf pipeline + 3-slot counted-vmcnt(4) ledger = R13 gemm_r structure,
// bf16 flavor (NPH=32, one 16x16x32 MFMA per (m,n) per phase).
#define KPHASEX(BFC, BFN, SLNXT, STAGEQ, DOSTAGE, WAITSTR, DOBAR)             \
  {                                                                           \
    if (DOSTAGE) STAGE(STAGEQ);                                               \
    const unsigned char* sln_ = (SLNXT);                                      \
    _Pragma("unroll") for (int n_ = 0; n_ < 4; ++n_)                          \
        BFN[n_] = *reinterpret_cast<const bf16x8*>(sln_ + offB[n_]);          \
    __builtin_amdgcn_s_setprio(1);                                            \
    _Pragma("unroll") for (int m_ = 0; m_ < 4; ++m_) {                        \
      _Pragma("unroll") for (int n_ = 0; n_ < 4; ++n_)                        \
          acc[m_][n_] = __builtin_amdgcn_mfma_f32_16x16x32_bf16(              \
              af[m_], BFC[n_], acc[m_][n_], 0, 0, 0);                         \
      af[m_] = *reinterpret_cast<const bf16x8*>(sln_ + offA[m_]);             \
    }                                                                         \
    __builtin_amdgcn_s_setprio(0);                                            \
    asm volatile(WAITSTR ::: "memory");                                       \
    __builtin_amdgcn_sched_barrier(0);                                        \
    if (DOBAR) {                                                              \
      __builtin_amdgcn_s_barrier();                                           \
      __builtin_amdgcn_sched_barrier(0);                                      \
    }                                                                         \
  }

__global__ __launch_bounds__(256, 3) void gemm_x(
    const unsigned short* __restrict__ A,    // xb bf16 [4096][1024]
    const unsigned short* __restrict__ Bm,   // Wbp bf16 [4096][1024]
    unsigned short* __restrict__ xpb_w,      // [B,4H] bf16 (proj+bias)
    const float* __restrict__ bp,            // [4H]
    unsigned short* __restrict__ ct,         // [B,H] bf16
    unsigned char* __restrict__ htimg) {     // [B,1024] fp8 image
  constexpr int N = 4096;
  constexpr int NPH = 32;      // K=1024, 32 elems/phase
  constexpr int SLOT = 16384;  // A [0,8192) 128r x 64B ; B [8192,16384)
  __shared__ unsigned char lds[3 * SLOT];  // 48KB; epilogue cs 128x132x2 fits

  const int tid = threadIdx.x;
  const int lane = tid & 63;
  const int wave = tid >> 6;
  const int wr = wave >> 1, wc = wave & 1;  // 2x2 waves, per-wave 64x64
  const int bid = blockIdx.x;
  const int sw = (bid & 7) * 128 + (bid >> 3);  // nwg=1024, %8==0
  const int brow = (sw >> 5) * 128, bcol = (sw & 31) * 128;

  const int physA0 = tid * 16, physA1 = 4096 + tid * 16;
  const int physB0 = 8192 + tid * 16, physB1 = 12288 + tid * 16;
  const int LA0 = swz(tid * 16), LA1 = swz(4096 + tid * 16);
  const unsigned char* pA0 = (const unsigned char*)A + (size_t)(brow + (LA0 >> 6)) * 2048 + (LA0 & 63);
  const unsigned char* pA1 = (const unsigned char*)A + (size_t)(brow + (LA1 >> 6)) * 2048 + (LA1 & 63);
  const unsigned char* pB0 = (const unsigned char*)Bm + (size_t)(bcol + (LA0 >> 6)) * 2048 + (LA0 & 63);
  const unsigned char* pB1 = (const unsigned char*)Bm + (size_t)(bcol + (LA1 >> 6)) * 2048 + (LA1 & 63);

  const int s16 = (lane >> 4) * 16;
  int offA[4], offB[4];
#pragma unroll
  for (int m = 0; m < 4; ++m)
    offA[m] = swz((wr * 64 + m * 16 + (lane & 15)) * 64 + s16);
#pragma unroll
  for (int n = 0; n < 4; ++n)
    offB[n] = 8192 + swz((wc * 64 + n * 16 + (lane & 15)) * 64 + s16);

  f32x4 acc[4][4] = {};
  bf16x8 af[4], bfE[4], bfO[4];

  auto STAGE = [&](int q) {
    unsigned char* sb = lds + (q % 3) * SLOT;
    const size_t kb = (size_t)q * 64;  // 32 bf16 elems = 64B per phase
    load_lds16(pA0 + kb, sb + physA0);
    load_lds16(pA1 + kb, sb + physA1);
    load_lds16(pB0 + kb, sb + physB0);
    load_lds16(pB1 + kb, sb + physB1);
  };

  // prologue: slots 0,1,2 issued (12 loads/wave); vmcnt(4) retires slots 0,1
  STAGE(0); STAGE(1); STAGE(2);
  asm volatile("s_waitcnt vmcnt(4)" ::: "memory");
  __builtin_amdgcn_s_barrier();
#pragma unroll
  for (int n = 0; n < 4; ++n) bfE[n] = *reinterpret_cast<const bf16x8*>(lds + offB[n]);
#pragma unroll
  for (int m = 0; m < 4; ++m) af[m] = *reinterpret_cast<const bf16x8*>(lds + offA[m]);
  asm volatile("s_waitcnt lgkmcnt(0)" ::: "memory");
  __builtin_amdgcn_sched_barrier(0);
  __builtin_amdgcn_s_barrier();  // slot 0 protected until all preloads done
  __builtin_amdgcn_sched_barrier(0);

  // phases 0..27: stage p+3, vmcnt(4)
  for (int pp = 0; pp < 14; ++pp) {
    const int p = 2 * pp;
    const unsigned char* sl1 = lds + ((p + 1) % 3) * SLOT;
    const unsigned char* sl2 = lds + ((p + 2) % 3) * SLOT;
    KPHASEX(bfE, bfO, sl1, p + 3, true, "s_waitcnt vmcnt(4) lgkmcnt(0)", true);
    KPHASEX(bfO, bfE, sl2, p + 4, true, "s_waitcnt vmcnt(4) lgkmcnt(0)", true);
  }
  // p=28: stage 31, vmcnt(4); p=29: vmcnt(0); p=30: lgkm only, no barrier
  KPHASEX(bfE, bfO, lds + (29 % 3) * SLOT, 31, true, "s_waitcnt vmcnt(4) lgkmcnt(0)", true);
  KPHASEX(bfO, bfE, lds + (30 % 3) * SLOT, 0, false, "s_waitcnt vmcnt(0) lgkmcnt(0)", true);
  KPHASEX(bfE, bfO, lds + (31 % 3) * SLOT, 0, false, "s_waitcnt lgkmcnt(0)", false);
  // p=31: MFMA only
  __builtin_amdgcn_s_setprio(1);
#pragma unroll
  for (int m = 0; m < 4; ++m)
#pragma unroll
    for (int n = 0; n < 4; ++n)
      acc[m][n] = __builtin_amdgcn_mfma_f32_16x16x32_bf16(af[m], bfO[n], acc[m][n], 0, 0, 0);
  __builtin_amdgcn_s_setprio(0);

  // ---- epilogue: stage bf16 tile (128x128, stride 132)
  __syncthreads();
  unsigned short* cs = (unsigned short*)lds;
  {
    const int c0 = wc * 64 + (lane & 15);
    const int r00 = wr * 64 + ((lane >> 4) << 2);
#pragma unroll
    for (int m = 0; m < 4; ++m)
#pragma unroll
      for (int n = 0; n < 4; ++n) {
        const int rr = r00 + m * 16, cc = c0 + n * 16;
#pragma unroll
        for (int r = 0; r < 4; ++r) cs[(rr + r) * 132 + cc] = f2b(acc[m][n][r]);
      }
  }
  __syncthreads();

  // ---- fused MODE-0 gates: 128 rows x 32 h per block -> 1024 quads, 4 iters
  const int hbase = bcol >> 2;
#pragma unroll 2
  for (int j = 0; j < 4; ++j) {
    const int v = tid + (j << 8);   // 0..1023
    const int row = v >> 3;         // 0..127
    const int h4 = (v & 7) << 2;    // 0..28
    const int ci = (brow + row) * 1024 + hbase + h4;

    unsigned short pvv[16];
    *reinterpret_cast<uint4*>(&pvv[0]) = *reinterpret_cast<const uint4*>(&cs[row * 132 + h4 * 4]);
    *reinterpret_cast<uint4*>(&pvv[8]) = *reinterpret_cast<const uint4*>(&cs[row * 132 + h4 * 4 + 8]);

    float bpf[16];
#pragma unroll
    for (int q = 0; q < 4; ++q)
      *reinterpret_cast<float4*>(&bpf[q * 4]) =
          *reinterpret_cast<const float4*>(&bp[bcol + h4 * 4 + q * 4]);

    float sf[4], si_[4], so_[4], sg_[4];
    unsigned short xo[16];
#pragma unroll
    for (int k = 0; k < 4; ++k) {
      sf[k] = b2f(pvv[4 * k + 0]) + bpf[4 * k + 0];
      si_[k] = b2f(pvv[4 * k + 1]) + bpf[4 * k + 1];
      so_[k] = b2f(pvv[4 * k + 2]) + bpf[4 * k + 2];
      sg_[k] = b2f(pvv[4 * k + 3]) + bpf[4 * k + 3];
      xo[4 * k + 0] = f2b(sf[k]);
      xo[4 * k + 1] = f2b(si_[k]);
      xo[4 * k + 2] = f2b(so_[k]);
      xo[4 * k + 3] = f2b(sg_[k]);
    }
    unsigned short* xw = &xpb_w[(size_t)(brow + row) * N + bcol + h4 * 4];
    *reinterpret_cast<uint4*>(xw) = *reinterpret_cast<const uint4*>(&xo[0]);
    *reinterpret_cast<uint4*>(xw + 8) = *reinterpret_cast<const uint4*>(&xo[8]);

    float cn[4], hn[4];
#pragma unroll
    for (int k = 0; k < 4; ++k) {
      const float ii = sigm(si_[k]);
      const float o = sigm(so_[k]);
      const float gg = tanh_fast(sg_[k]);
      const float c = ii * gg;  // f*0 + i*g
      cn[k] = c;
      hn[k] = o * tanh_fast(c);
    }
    ushort4 cb;
    cb.x = f2b(cn[0]); cb.y = f2b(cn[1]); cb.z = f2b(cn[2]); cb.w = f2b(cn[3]);
    *reinterpret_cast<ushort4*>(&ct[ci]) = cb;
    const int hc0 = hbase + h4;
    uchar4 h8;
    h8.x = f2fp8(hn[0] * 16.f); h8.y = f2fp8(hn[1] * 16.f);
    h8.z = f2fp8(hn[2] * 16.f); h8.w = f2fp8(hn[3] * 16.f);
    *reinterpret_cast<uchar4*>(&htimg[(size_t)(brow + row) * 1024 + imgk(hc0)]) = h8;
  }
}

// ============================ fp8 GEMM (t=1..7), high-occupancy (R13-verified)
#define KPHASE8(BFC, BFN, SLNXT, STAGEQ, DOSTAGE, WAITSTR, DOBAR)             \
  {                                                                           \
    if (DOSTAGE) STAGE(STAGEQ);                                               \
    const unsigned char* sln_ = (SLNXT);                                      \
    _Pragma("unroll") for (int n_ = 0; n_ < 4; ++n_)                          \
        BFN[n_] = *reinterpret_cast<const i64x2*>(sln_ + offB[n_]);           \
    __builtin_amdgcn_s_setprio(1);                                            \
    _Pragma("unroll") for (int m_ = 0; m_ < 4; ++m_) {                        \
      _Pragma("unroll") for (int n_ = 0; n_ < 4; ++n_)                        \
          acc[m_][n_] = __builtin_amdgcn_mfma_f32_16x16x32_fp8_fp8(           \
              af[m_][0], BFC[n_][0], acc[m_][n_], 0, 0, 0);                   \
      _Pragma("unroll") for (int n_ = 0; n_ < 4; ++n_)                        \
          acc[m_][n_] = __builtin_amdgcn_mfma_f32_16x16x32_fp8_fp8(           \
              af[m_][1], BFC[n_][1], acc[m_][n_], 0, 0, 0);                   \
      af[m_] = *reinterpret_cast<const i64x2*>(sln_ + offA[m_]);              \
    }                                                                         \
    __builtin_amdgcn_s_setprio(0);                                            \
    asm volatile(WAITSTR ::: "memory");                                       \
    __builtin_amdgcn_sched_barrier(0);                                        \
    if (DOBAR) {                                                              \
      __builtin_amdgcn_s_barrier();                                           \
      __builtin_amdgcn_sched_barrier(0);                                      \
    }                                                                         \
  }

template <bool LAST>
__global__ __launch_bounds__(256, 3) void gemm_r(
    const unsigned char* __restrict__ Aimg,  // ht fp8 image [4096][1024]
    const unsigned char* __restrict__ Bimg,  // Up8 image [4096][1024]
    const unsigned short* __restrict__ xpb_r,
    unsigned short* __restrict__ ct,
    unsigned char* __restrict__ htimg,
    float* __restrict__ out) {
  constexpr int N = 4096;
  constexpr int SLOT = 16384;  // A [0,8192) 128r x 64B ; B [8192,16384)
  __shared__ unsigned char lds[3 * SLOT];

  const int tid = threadIdx.x;
  const int lane = tid & 63;
  const int wave = tid >> 6;
  const int wr = wave >> 1, wc = wave & 1;
  const int bid = blockIdx.x;
  const int sw = (bid & 7) * 128 + (bid >> 3);
  const int brow = (sw >> 5) * 128, bcol = (sw & 31) * 128;

  const int physA0 = tid * 16, physA1 = 4096 + tid * 16;
  const int physB0 = 8192 + tid * 16, physB1 = 12288 + tid * 16;
  const int LA0 = swz(tid * 16), LA1 = swz(4096 + tid * 16);
  const unsigned char* pA0 = Aimg + (size_t)(brow + (LA0 >> 6)) * 1024 + (LA0 & 63);
  const unsigned char* pA1 = Aimg + (size_t)(brow + (LA1 >> 6)) * 1024 + (LA1 & 63);
  const unsigned char* pB0 = Bimg + (size_t)(bcol + (LA0 >> 6)) * 1024 + (LA0 & 63);
  const unsigned char* pB1 = Bimg + (size_t)(bcol + (LA1 >> 6)) * 1024 + (LA1 & 63);

  const int s16 = (lane >> 4) * 16;
  int offA[4], offB[4];
#pragma unroll
  for (int m = 0; m < 4; ++m)
    offA[m] = swz((wr * 64 + m * 16 + (lane & 15)) * 64 + s16);
#pragma unroll
  for (int n = 0; n < 4; ++n)
    offB[n] = 8192 + swz((wc * 64 + n * 16 + (lane & 15)) * 64 + s16);

  f32x4 acc[4][4] = {};
  i64x2 af[4], bfE[4], bfO[4];

  auto STAGE = [&](int q) {
    unsigned char* sb = lds + (q % 3) * SLOT;
    const size_t kb = (size_t)q * 64;
    load_lds16(pA0 + kb, sb + physA0);
    load_lds16(pA1 + kb, sb + physA1);
    load_lds16(pB0 + kb, sb + physB0);
    load_lds16(pB1 + kb, sb + physB1);
  };

  STAGE(0); STAGE(1); STAGE(2);
  asm volatile("s_waitcnt vmcnt(4)" ::: "memory");
  __builtin_amdgcn_s_barrier();
#pragma unroll
  for (int n = 0; n < 4; ++n) bfE[n] = *reinterpret_cast<const i64x2*>(lds + offB[n]);
#pragma unroll
  for (int m = 0; m < 4; ++m) af[m] = *reinterpret_cast<const i64x2*>(lds + offA[m]);
  asm volatile("s_waitcnt lgkmcnt(0)" ::: "memory");
  __builtin_amdgcn_sched_barrier(0);
  __builtin_amdgcn_s_barrier();
  __builtin_amdgcn_sched_barrier(0);

  for (int pp = 0; pp < 6; ++pp) {
    const int p = 2 * pp;
    const unsigned char* sl1 = lds + ((p + 1) % 3) * SLOT;
    const unsigned char* sl2 = lds + ((p + 2) % 3) * SLOT;
    KPHASE8(bfE, bfO, sl1, p + 3, true, "s_waitcnt vmcnt(4) lgkmcnt(0)", true);
    KPHASE8(bfO, bfE, sl2, p + 4, true, "s_waitcnt vmcnt(4) lgkmcnt(0)", true);
  }
  KPHASE8(bfE, bfO, lds + (13 % 3) * SLOT, 15, true, "s_waitcnt vmcnt(4) lgkmcnt(0)", true);
  KPHASE8(bfO, bfE, lds + (14 % 3) * SLOT, 0, false, "s_waitcnt vmcnt(0) lgkmcnt(0)", true);
  KPHASE8(bfE, bfO, lds + (15 % 3) * SLOT, 0, false, "s_waitcnt lgkmcnt(0)", false);
  __builtin_amdgcn_s_setprio(1);
#pragma unroll
  for (int m = 0; m < 4; ++m) {
#pragma unroll
    for (int n = 0; n < 4; ++n)
      acc[m][n] = __builtin_amdgcn_mfma_f32_16x16x32_fp8_fp8(af[m][0], bfO[n][0], acc[m][n], 0, 0, 0);
#pragma unroll
    for (int n = 0; n < 4; ++n)
      acc[m][n] = __builtin_amdgcn_mfma_f32_16x16x32_fp8_fp8(af[m][1], bfO[n][1], acc[m][n], 0, 0, 0);
  }
  __builtin_amdgcn_s_setprio(0);

  __syncthreads();
  unsigned short* cs = (unsigned short*)lds;
  {
    const float inv = 1.0f / 512.0f;
    const int c0 = wc * 64 + (lane & 15);
    const int r00 = wr * 64 + ((lane >> 4) << 2);
#pragma unroll
    for (int m = 0; m < 4; ++m)
#pragma unroll
      for (int n = 0; n < 4; ++n) {
        const int rr = r00 + m * 16, cc = c0 + n * 16;
#pragma unroll
        for (int r = 0; r < 4; ++r) cs[(rr + r) * 132 + cc] = f2b(acc[m][n][r] * inv);
      }
  }
  __syncthreads();

  const int hbase = bcol >> 2;
#pragma unroll 2
  for (int j = 0; j < 4; ++j) {
    const int v = tid + (j << 8);
    const int row = v >> 3;
    const int h4 = (v & 7) << 2;
    const int ci = (brow + row) * 1024 + hbase + h4;

    unsigned short pvv[16], xvv[16];
    *reinterpret_cast<uint4*>(&pvv[0]) = *reinterpret_cast<const uint4*>(&cs[row * 132 + h4 * 4]);
    *reinterpret_cast<uint4*>(&pvv[8]) = *reinterpret_cast<const uint4*>(&cs[row * 132 + h4 * 4 + 8]);
    const unsigned short* xr = &xpb_r[(size_t)(brow + row) * N + bcol + h4 * 4];
    *reinterpret_cast<uint4*>(&xvv[0]) = *reinterpret_cast<const uint4*>(xr);
    *reinterpret_cast<uint4*>(&xvv[8]) = *reinterpret_cast<const uint4*>(xr + 8);

    const ushort4 cv = *reinterpret_cast<const ushort4*>(&ct[ci]);
    float c_old[4] = {b2f(cv.x), b2f(cv.y), b2f(cv.z), b2f(cv.w)};

    float cn[4], hn[4];
#pragma unroll
    for (int k = 0; k < 4; ++k) {
      const float f = sigm(b2f(pvv[4 * k + 0]) + b2f(xvv[4 * k + 0]));
      const float ii = sigm(b2f(pvv[4 * k + 1]) + b2f(xvv[4 * k + 1]));
      const float o = sigm(b2f(pvv[4 * k + 2]) + b2f(xvv[4 * k + 2]));
      const float gg = tanh_fast(b2f(pvv[4 * k + 3]) + b2f(xvv[4 * k + 3]));
      const float c = fmaf(f, c_old[k], ii * gg);
      cn[k] = c;
      hn[k] = o * tanh_fast(c);
    }

    if constexpr (LAST) {
      *reinterpret_cast<float4*>(&out[ci]) = make_float4(hn[0], hn[1], hn[2], hn[3]);
      *reinterpret_cast<float4*>(&out[4194304 + ci]) = make_float4(cn[0], cn[1], cn[2], cn[3]);
    } else {
      ushort4 cb;
      cb.x = f2b(cn[0]); cb.y = f2b(cn[1]); cb.z = f2b(cn[2]); cb.w = f2b(cn[3]);
      *reinterpret_cast<ushort4*>(&ct[ci]) = cb;
      const int hc0 = hbase + h4;
      uchar4 h8;
      h8.x = f2fp8(hn[0] * 16.f); h8.y = f2fp8(hn[1] * 16.f);
      h8.z = f2fp8(hn[2] * 16.f); h8.w = f2fp8(hn[3] * 16.f);
      *reinterpret_cast<uchar4*>(&htimg[(size_t)(brow + row) * 1024 + imgk(hc0)]) = h8;
    }
  }
}

// ---------------------------------------------------------------- launch
extern "C" void kernel_launch(void* const* d_in, const int* in_sizes, int n_in,
                              void* d_out, int out_size, void* d_ws, size_t ws_size,
                              hipStream_t stream) {
  const float* x = (const float*)d_in[0];
  const float* W = (const float*)d_in[1];
  const float* bW = (const float*)d_in[2];
  const float* U = (const float*)d_in[3];
  const float* bU = (const float*)d_in[4];
  float* out = (float*)d_out;

  char* w = (char*)d_ws;
  const size_t MB = 1ull << 20;
  unsigned short* xb = (unsigned short*)(w + 0 * MB);    // 8 MB bf16
  unsigned short* Wbp = (unsigned short*)(w + 8 * MB);   // 8 MB bf16 (gate-interleaved)
  unsigned char* Up8 = (unsigned char*)(w + 16 * MB);    // 4 MB fp8 image (x32)
  unsigned short* xpb = (unsigned short*)(w + 24 * MB);  // 32 MB bf16 proj+bias
  unsigned short* ct = (unsigned short*)(w + 56 * MB);   // 8 MB bf16 state
  unsigned char* htA = (unsigned char*)(w + 64 * MB);    // 4 MB fp8 image (x16)
  unsigned char* htB = (unsigned char*)(w + 68 * MB);    // 4 MB fp8 image
  float* bp = (float*)(w + 72 * MB);                     // 16 KB

  prep_kernel<<<9232, 256, 0, stream>>>(x, W, U, bW, bU, xb, Wbp, Up8, bp);

  gemm_x<<<1024, 256, 0, stream>>>(xb, Wbp, xpb, bp, ct, htA);

  const unsigned char* hin = htA;
  unsigned char* hout = htB;
  for (int t = 1; t <= 6; ++t) {
    gemm_r<false><<<1024, 256, 0, stream>>>(hin, Up8, xpb, ct, hout, nullptr);
    const unsigned char* tmp = hout;
    hout = (unsigned char*)hin;
    hin = tmp;
  }
  gemm_r<true><<<1024, 256, 0, stream>>>(hin, Up8, xpb, ct, nullptr, out);
}